// Round 11
// baseline (482.052 us; speedup 1.0000x reference)
//
#include <hip/hip_runtime.h>
#include <hip/hip_cooperative_groups.h>
#include <math.h>
#include <stdint.h>

// CausalRevIN: B=16, T=8192, C=128, fp32.
// R11: k1 (cold window) unchanged from R10; k2+k3 merged into ONE cooperative
// kernel with a single grid.sync. x held in 16 f32x4 regs across the sync
// (R8's spill came from TWO syncs + extra state); mean recomputed in sweep B.
// Fallback (coop launch failure): R10's 3-kernel path.
constexpr int B = 16;
constexpr int T = 8192;
constexpr int C = 128;
constexpr int CG = C / 4;        // 32 f32x4 channel-groups
constexpr int TBK = 128;         // rows per chunk/block
constexpr int NCH = T / TBK;     // 64 chunks per batch
constexpr int SUBS = 8;          // 256 threads = SUBS * CG
constexpr int RPT = TBK / SUBS;  // 16 rows per thread
constexpr float STD_MIN = 1e-5f;
constexpr float MAX_VAL = 100.0f;

using f32x4 = __attribute__((ext_vector_type(4))) float;

__device__ inline f32x4 max1(f32x4 n) {
    f32x4 r;
    #pragma unroll
    for (int j = 0; j < 4; ++j) r[j] = fmaxf(n[j], 1.0f);
    return r;
}
__device__ inline f32x4 rcp4(f32x4 a) {
    f32x4 r;
    #pragma unroll
    for (int j = 0; j < 4; ++j) r[j] = __builtin_amdgcn_rcpf(a[j]);
    return r;
}
__device__ inline f32x4 sqrt4(f32x4 a) {
    f32x4 r;
    #pragma unroll
    for (int j = 0; j < 4; ++j) r[j] = __builtin_amdgcn_sqrtf(a[j]);
    return r;
}
__device__ inline f32x4 decode_nib(unsigned nib) {
    f32x4 r;
    r[0] = (float)(nib & 1u);
    r[1] = (float)((nib >> 1) & 1u);
    r[2] = (float)((nib >> 2) & 1u);
    r[3] = (float)((nib >> 3) & 1u);
    return r;
}

// ---------------- k1: cold sums + sub partials + nm nibbles ----------------
__global__ __launch_bounds__(256) void k1_sums(
    const f32x4* __restrict__ x, const f32x4* __restrict__ mask,
    f32x4* __restrict__ aggx, f32x4* __restrict__ aggn,
    f32x4* __restrict__ subx, f32x4* __restrict__ subn,
    uint64_t* __restrict__ nmw)
{
    __shared__ f32x4 p0[SUBS][CG], p1[SUBS][CG];
    int tid = threadIdx.x, cg = tid & 31, sub = tid >> 5;
    int blk = blockIdx.x, b = blk >> 6, k = blk & (NCH - 1);
    size_t base = ((size_t)b * T + (size_t)k * TBK + (size_t)sub * RPT) * CG + cg;

    f32x4 sx = {0,0,0,0}, sn = {0,0,0,0};
    uint64_t w = 0;
    #pragma unroll
    for (int r = 0; r < RPT; ++r) {
        f32x4 xv = x[base + (size_t)r * CG];
        f32x4 mv = mask[base + (size_t)r * CG];
        f32x4 nm = 1.0f - mv;
        sx += xv; sn += nm;
        unsigned nib = (unsigned)nm[0] | ((unsigned)nm[1] << 1)
                     | ((unsigned)nm[2] << 2) | ((unsigned)nm[3] << 3);
        w |= (uint64_t)nib << (4 * r);
    }
    nmw[(size_t)blk * 256 + tid] = w;
    size_t so = ((size_t)blk * SUBS + sub) * CG + cg;
    subx[so] = sx;
    subn[so] = sn;
    p0[sub][cg] = sx; p1[sub][cg] = sn;
    __syncthreads();
    if (sub == 0) {
        f32x4 tx = p0[0][cg], tn = p1[0][cg];
        #pragma unroll
        for (int s = 1; s < SUBS; ++s) { tx += p0[s][cg]; tn += p1[s][cg]; }
        aggx[(size_t)blk * CG + cg] = tx;
        aggn[(size_t)blk * CG + cg] = tn;
    }
}

// ---------------- k23: cooperative dev^2 + finalize (one grid.sync) --------
__global__ __launch_bounds__(256, 4) void k23_fused(
    const f32x4* __restrict__ x,
    const f32x4* __restrict__ aggx, const f32x4* __restrict__ aggn,
    const f32x4* __restrict__ subx, const f32x4* __restrict__ subn,
    const uint64_t* __restrict__ nmw,
    f32x4* __restrict__ aggd, f32x4* __restrict__ out)
{
    namespace cg_ns = cooperative_groups;
    cg_ns::grid_group gridg = cg_ns::this_grid();

    __shared__ f32x4 p0[SUBS][CG], p1[SUBS][CG];   // 8 KB
    int tid = threadIdx.x, cg = tid & 31, sub = tid >> 5;
    int blk = blockIdx.x, b = blk >> 6, k = blk & (NCH - 1);
    size_t base = ((size_t)b * T + (size_t)k * TBK + (size_t)sub * RPT) * CG + cg;

    // --- prologue: chunk prefix (x, nm) + own-sub offsets ------------------
    f32x4 pxp = {0,0,0,0}, pnp = {0,0,0,0};
    for (int j = sub; j < k; j += SUBS) {
        size_t o = ((size_t)(b * NCH + j)) * CG + cg;
        pxp += aggx[o]; pnp += aggn[o];
    }
    p0[sub][cg] = pxp; p1[sub][cg] = pnp;
    __syncthreads();
    f32x4 px = p0[0][cg], pn = p1[0][cg];
    #pragma unroll
    for (int s = 1; s < SUBS; ++s) { px += p0[s][cg]; pn += p1[s][cg]; }

    f32x4 offx = {0,0,0,0}, offn = {0,0,0,0};
    for (int s = 0; s < sub; ++s) {
        size_t so = ((size_t)blk * SUBS + s) * CG + cg;
        offx += subx[so]; offn += subn[so];
    }
    f32x4 rx0 = px + offx, rn0 = pn + offn;
    uint64_t w = nmw[(size_t)blk * 256 + tid];

    // --- sweep A: load x into regs; running mean -> dev^2 sums -------------
    f32x4 xr[RPT];
    f32x4 rx = rx0, rn = rn0, sd = {0,0,0,0};
    #pragma unroll
    for (int r = 0; r < RPT; ++r) {
        f32x4 xv = x[base + (size_t)r * CG];
        xr[r] = xv;
        f32x4 nm = decode_nib((unsigned)(w >> (4 * r)) & 0xFu);
        rx += xv; rn += nm;
        f32x4 mean = rx * rcp4(max1(rn));
        f32x4 d = (xv - mean) * nm;
        sd += d * d;
    }
    __syncthreads();            // prologue reads of p0/p1 complete
    p0[sub][cg] = sd;
    __syncthreads();
    f32x4 offd = {0,0,0,0};
    for (int s = 0; s < sub; ++s) offd += p0[s][cg];
    if (sub == 0) {
        f32x4 td = p0[0][cg];
        #pragma unroll
        for (int s = 1; s < SUBS; ++s) td += p0[s][cg];
        aggd[(size_t)blk * CG + cg] = td;
    }
    __threadfence();
    gridg.sync();

    // --- prologue 2: chunk prefix (d2) -------------------------------------
    f32x4 pdp = {0,0,0,0};
    for (int j = sub; j < k; j += SUBS)
        pdp += aggd[((size_t)(b * NCH + j)) * CG + cg];
    p1[sub][cg] = pdp;
    __syncthreads();
    f32x4 pd = p1[0][cg];
    #pragma unroll
    for (int s = 1; s < SUBS; ++s) pd += p1[s][cg];
    f32x4 rd = pd + offd;

    // --- sweep B: finalize + clip + NT store (x from registers) ------------
    rx = rx0; rn = rn0;
    #pragma unroll
    for (int r = 0; r < RPT; ++r) {
        f32x4 nm = decode_nib((unsigned)(w >> (4 * r)) & 0xFu);
        rx += xr[r]; rn += nm;
        f32x4 inv = rcp4(max1(rn));
        f32x4 mean = rx * inv;
        f32x4 d = (xr[r] - mean) * nm;
        rd += d * d;
        f32x4 s = sqrt4(rd * inv);
        f32x4 ov;
        #pragma unroll
        for (int j = 0; j < 4; ++j) {
            float invs = (s[j] > STD_MIN) ? __builtin_amdgcn_rcpf(s[j]) : 1.0f;
            float v = (xr[r][j] - mean[j]) * invs;
            ov[j] = fminf(fmaxf(v, -MAX_VAL), MAX_VAL);
        }
        __builtin_nontemporal_store(ov, &out[base + (size_t)r * CG]);
    }
}

// ---------------- fallback: R10 k2/k3 --------------------------------------
__global__ __launch_bounds__(256) void k2_dev2(
    const f32x4* __restrict__ x,
    const f32x4* __restrict__ aggx, const f32x4* __restrict__ aggn,
    const f32x4* __restrict__ subx, const f32x4* __restrict__ subn,
    const uint64_t* __restrict__ nmw,
    f32x4* __restrict__ aggd, f32x4* __restrict__ subd)
{
    __shared__ f32x4 p0[SUBS][CG], p1[SUBS][CG];
    int tid = threadIdx.x, cg = tid & 31, sub = tid >> 5;
    int blk = blockIdx.x, b = blk >> 6, k = blk & (NCH - 1);
    size_t base = ((size_t)b * T + (size_t)k * TBK + (size_t)sub * RPT) * CG + cg;

    f32x4 pxp = {0,0,0,0}, pnp = {0,0,0,0};
    for (int j = sub; j < k; j += SUBS) {
        size_t o = ((size_t)(b * NCH + j)) * CG + cg;
        pxp += aggx[o]; pnp += aggn[o];
    }
    p0[sub][cg] = pxp; p1[sub][cg] = pnp;
    __syncthreads();
    f32x4 px = p0[0][cg], pn = p1[0][cg];
    #pragma unroll
    for (int s = 1; s < SUBS; ++s) { px += p0[s][cg]; pn += p1[s][cg]; }

    f32x4 offx = {0,0,0,0}, offn = {0,0,0,0};
    for (int s = 0; s < sub; ++s) {
        size_t so = ((size_t)blk * SUBS + s) * CG + cg;
        offx += subx[so]; offn += subn[so];
    }
    f32x4 rx = px + offx, rn = pn + offn;
    uint64_t w = nmw[(size_t)blk * 256 + tid];

    f32x4 sd = {0,0,0,0};
    #pragma unroll
    for (int r = 0; r < RPT; ++r) {
        f32x4 xv = x[base + (size_t)r * CG];
        f32x4 nm = decode_nib((unsigned)(w >> (4 * r)) & 0xFu);
        rx += xv; rn += nm;
        f32x4 mean = rx * rcp4(max1(rn));
        f32x4 d = (xv - mean) * nm;
        sd += d * d;
    }
    subd[((size_t)blk * SUBS + sub) * CG + cg] = sd;
    __syncthreads();
    p0[sub][cg] = sd;
    __syncthreads();
    if (sub == 0) {
        f32x4 td = p0[0][cg];
        #pragma unroll
        for (int s = 1; s < SUBS; ++s) td += p0[s][cg];
        aggd[(size_t)blk * CG + cg] = td;
    }
}

__global__ __launch_bounds__(256) void k3_final(
    const f32x4* __restrict__ x,
    const f32x4* __restrict__ aggx, const f32x4* __restrict__ aggn,
    const f32x4* __restrict__ aggd,
    const f32x4* __restrict__ subx, const f32x4* __restrict__ subn,
    const f32x4* __restrict__ subd,
    const uint64_t* __restrict__ nmw, f32x4* __restrict__ out)
{
    __shared__ f32x4 p0[SUBS][CG], p1[SUBS][CG], p2[SUBS][CG];
    int tid = threadIdx.x, cg = tid & 31, sub = tid >> 5;
    int blk = blockIdx.x, b = blk >> 6, k = blk & (NCH - 1);
    size_t base = ((size_t)b * T + (size_t)k * TBK + (size_t)sub * RPT) * CG + cg;

    f32x4 pxp = {0,0,0,0}, pnp = {0,0,0,0}, pdp = {0,0,0,0};
    for (int j = sub; j < k; j += SUBS) {
        size_t o = ((size_t)(b * NCH + j)) * CG + cg;
        pxp += aggx[o]; pnp += aggn[o]; pdp += aggd[o];
    }
    p0[sub][cg] = pxp; p1[sub][cg] = pnp; p2[sub][cg] = pdp;
    __syncthreads();
    f32x4 px = p0[0][cg], pn = p1[0][cg], pd = p2[0][cg];
    #pragma unroll
    for (int s = 1; s < SUBS; ++s) {
        px += p0[s][cg]; pn += p1[s][cg]; pd += p2[s][cg];
    }

    f32x4 offx = {0,0,0,0}, offn = {0,0,0,0}, offd = {0,0,0,0};
    for (int s = 0; s < sub; ++s) {
        size_t so = ((size_t)blk * SUBS + s) * CG + cg;
        offx += subx[so]; offn += subn[so]; offd += subd[so];
    }
    f32x4 rx = px + offx, rn = pn + offn, rd = pd + offd;
    uint64_t w = nmw[(size_t)blk * 256 + tid];

    #pragma unroll
    for (int r = 0; r < RPT; ++r) {
        f32x4 xv = x[base + (size_t)r * CG];
        f32x4 nm = decode_nib((unsigned)(w >> (4 * r)) & 0xFu);
        rx += xv; rn += nm;
        f32x4 inv = rcp4(max1(rn));
        f32x4 mean = rx * inv;
        f32x4 d = (xv - mean) * nm;
        rd += d * d;
        f32x4 s = sqrt4(rd * inv);
        f32x4 ov;
        #pragma unroll
        for (int j = 0; j < 4; ++j) {
            float invs = (s[j] > STD_MIN) ? __builtin_amdgcn_rcpf(s[j]) : 1.0f;
            float v = (xv[j] - mean[j]) * invs;
            ov[j] = fminf(fmaxf(v, -MAX_VAL), MAX_VAL);
        }
        __builtin_nontemporal_store(ov, &out[base + (size_t)r * CG]);
    }
}

// ===========================================================================
extern "C" void kernel_launch(void* const* d_in, const int* in_sizes, int n_in,
                              void* d_out, int out_size, void* d_ws, size_t ws_size,
                              hipStream_t stream) {
    const f32x4* x    = (const f32x4*)d_in[0];
    const f32x4* mask = (const f32x4*)d_in[1];
    f32x4* out = (f32x4*)d_out;

    // ws: aggx/aggn/aggd (512 KB each) + subx/subn/subd (4 MB each) + nmw (2 MB)
    size_t agg_elems = (size_t)B * NCH * CG;          // 32768 f32x4
    size_t sub_elems = (size_t)B * NCH * SUBS * CG;   // 262144 f32x4
    f32x4* aggx = (f32x4*)d_ws;
    f32x4* aggn = aggx + agg_elems;
    f32x4* aggd = aggn + agg_elems;
    f32x4* subx = aggd + agg_elems;
    f32x4* subn = subx + sub_elems;
    f32x4* subd = subn + sub_elems;
    uint64_t* nmw = (uint64_t*)(subd + sub_elems);

    int grid = B * NCH;   // 1024

    k1_sums<<<grid, 256, 0, stream>>>(x, mask, aggx, aggn, subx, subn, nmw);

    {
        const f32x4* xa = x;
        const f32x4* ax = aggx; const f32x4* an = aggn;
        const f32x4* sx = subx; const f32x4* sn = subn;
        const uint64_t* nw = nmw;
        f32x4* ad = aggd; f32x4* oo = out;
        void* args[] = { (void*)&xa, (void*)&ax, (void*)&an,
                         (void*)&sx, (void*)&sn, (void*)&nw,
                         (void*)&ad, (void*)&oo };
        hipError_t err = hipLaunchCooperativeKernel(
            reinterpret_cast<const void*>(&k23_fused),
            dim3(grid), dim3(256), args, 0, stream);
        if (err == hipSuccess) return;
    }

    // fallback: R10 path
    k2_dev2<<<grid, 256, 0, stream>>>(x, aggx, aggn, subx, subn, nmw, aggd, subd);
    k3_final<<<grid, 256, 0, stream>>>(x, aggx, aggn, aggd, subx, subn, subd, nmw, out);
}

// Round 12
// 376.936 us; speedup vs baseline: 1.2789x; 1.2789x over previous
//
#include <hip/hip_runtime.h>
#include <math.h>
#include <stdint.h>

// CausalRevIN: B=16, T=8192, C=128, fp32.
// R12: ONE kernel, no inter-block dependency, no workspace arrays.
// Block = (b, f32x4-column): grid 512, block owns full T for 4 channels;
// thread owns rows [32*tid, 32*tid+32). All prefixes are block-internal
// (shuffle+LDS exclusive scans). mask read once (nm bits -> 2 uint64 regs);
// x read 3x (1 cold-ish + 2 L3-warm); out NT-stored. No register x array,
// no grid.sync -> no spill (R8/R11 lesson).
constexpr int B = 16;
constexpr int T = 8192;
constexpr int C = 128;
constexpr int CG = C / 4;        // 32 f32x4 channel-groups
constexpr int RPT = 32;          // rows per thread (256 thr * 32 = 8192 = T)
constexpr float STD_MIN = 1e-5f;
constexpr float MAX_VAL = 100.0f;

using f32x4 = __attribute__((ext_vector_type(4))) float;

__device__ inline f32x4 max1(f32x4 n) {
    f32x4 r;
    #pragma unroll
    for (int j = 0; j < 4; ++j) r[j] = fmaxf(n[j], 1.0f);
    return r;
}
__device__ inline f32x4 rcp4(f32x4 a) {
    f32x4 r;
    #pragma unroll
    for (int j = 0; j < 4; ++j) r[j] = __builtin_amdgcn_rcpf(a[j]);
    return r;
}
__device__ inline f32x4 sqrt4(f32x4 a) {
    f32x4 r;
    #pragma unroll
    for (int j = 0; j < 4; ++j) r[j] = __builtin_amdgcn_sqrtf(a[j]);
    return r;
}
__device__ inline f32x4 decode_nib(unsigned nib) {
    f32x4 r;
    r[0] = (float)(nib & 1u);
    r[1] = (float)((nib >> 1) & 1u);
    r[2] = (float)((nib >> 2) & 1u);
    r[3] = (float)((nib >> 3) & 1u);
    return r;
}

// exclusive block scan over 256 threads (thread order), NCOMP floats each.
template <int NCOMP>
__device__ inline void block_exscan(float* vals, int lane, int wave)
{
    float inc[NCOMP];
    #pragma unroll
    for (int j = 0; j < NCOMP; ++j) inc[j] = vals[j];
    #pragma unroll
    for (int d = 1; d < 64; d <<= 1) {
        #pragma unroll
        for (int j = 0; j < NCOMP; ++j) {
            float u = __shfl_up(inc[j], d, 64);
            if (lane >= d) inc[j] += u;
        }
    }
    __shared__ float wsum[4][NCOMP];
    if (lane == 63) {
        #pragma unroll
        for (int j = 0; j < NCOMP; ++j) wsum[wave][j] = inc[j];
    }
    __syncthreads();
    float off[NCOMP];
    #pragma unroll
    for (int j = 0; j < NCOMP; ++j) off[j] = 0.0f;
    for (int w = 0; w < wave; ++w) {
        #pragma unroll
        for (int j = 0; j < NCOMP; ++j) off[j] += wsum[w][j];
    }
    #pragma unroll
    for (int j = 0; j < NCOMP; ++j) {
        float e = __shfl_up(inc[j], 1, 64);
        vals[j] = off[j] + ((lane == 0) ? 0.0f : e);
    }
}

__global__ __launch_bounds__(256) void k_all(
    const f32x4* __restrict__ x, const f32x4* __restrict__ mask,
    f32x4* __restrict__ out)
{
    int tid = threadIdx.x, lane = tid & 63, wave = tid >> 6;
    int blk = blockIdx.x, b = blk >> 5, cg = blk & 31;
    // thread's rows: [tid*RPT, tid*RPT+RPT) of column cg in batch b
    size_t base = ((size_t)b * T + (size_t)tid * RPT) * CG + cg;

    // ---- phase 1: read x+mask once; per-thread sums; nm bits -> regs ------
    f32x4 sx = {0,0,0,0}, sn = {0,0,0,0};
    uint64_t w0 = 0, w1 = 0;
    #pragma unroll 8
    for (int r = 0; r < RPT; ++r) {
        f32x4 xv = x[base + (size_t)r * CG];
        f32x4 mv = mask[base + (size_t)r * CG];
        f32x4 nm = 1.0f - mv;
        sx += xv; sn += nm;
        unsigned nib = (unsigned)nm[0] | ((unsigned)nm[1] << 1)
                     | ((unsigned)nm[2] << 2) | ((unsigned)nm[3] << 3);
        if (r < 16) w0 |= (uint64_t)nib << (4 * r);
        else        w1 |= (uint64_t)nib << (4 * (r - 16));
    }
    float v8[8] = {sx[0],sx[1],sx[2],sx[3],sn[0],sn[1],sn[2],sn[3]};
    block_exscan<8>(v8, lane, wave);
    f32x4 rx0 = {v8[0],v8[1],v8[2],v8[3]};
    f32x4 rn0 = {v8[4],v8[5],v8[6],v8[7]};

    // ---- phase 2: dev^2 sweep (x warm re-read); block scan of d2 ----------
    f32x4 rx = rx0, rn = rn0, sd = {0,0,0,0};
    #pragma unroll 8
    for (int r = 0; r < RPT; ++r) {
        f32x4 xv = x[base + (size_t)r * CG];
        unsigned nib = (r < 16) ? (unsigned)(w0 >> (4 * r)) & 0xFu
                                : (unsigned)(w1 >> (4 * (r - 16))) & 0xFu;
        f32x4 nm = decode_nib(nib);
        rx += xv; rn += nm;
        f32x4 mean = rx * rcp4(max1(rn));
        f32x4 d = (xv - mean) * nm;
        sd += d * d;
    }
    __syncthreads();   // block_exscan<8>'s wsum reads done before <4> reuse
    float v4[4] = {sd[0],sd[1],sd[2],sd[3]};
    block_exscan<4>(v4, lane, wave);
    f32x4 rd = {v4[0],v4[1],v4[2],v4[3]};

    // ---- phase 3: finalize + clip + NT store (x warm re-read) -------------
    rx = rx0; rn = rn0;
    #pragma unroll 8
    for (int r = 0; r < RPT; ++r) {
        f32x4 xv = x[base + (size_t)r * CG];
        unsigned nib = (r < 16) ? (unsigned)(w0 >> (4 * r)) & 0xFu
                                : (unsigned)(w1 >> (4 * (r - 16))) & 0xFu;
        f32x4 nm = decode_nib(nib);
        rx += xv; rn += nm;
        f32x4 inv = rcp4(max1(rn));
        f32x4 mean = rx * inv;
        f32x4 d = (xv - mean) * nm;
        rd += d * d;
        f32x4 s = sqrt4(rd * inv);
        f32x4 ov;
        #pragma unroll
        for (int j = 0; j < 4; ++j) {
            float invs = (s[j] > STD_MIN) ? __builtin_amdgcn_rcpf(s[j]) : 1.0f;
            float v = (xv[j] - mean[j]) * invs;
            ov[j] = fminf(fmaxf(v, -MAX_VAL), MAX_VAL);
        }
        __builtin_nontemporal_store(ov, &out[base + (size_t)r * CG]);
    }
}

// ===========================================================================
extern "C" void kernel_launch(void* const* d_in, const int* in_sizes, int n_in,
                              void* d_out, int out_size, void* d_ws, size_t ws_size,
                              hipStream_t stream) {
    const f32x4* x    = (const f32x4*)d_in[0];
    const f32x4* mask = (const f32x4*)d_in[1];
    f32x4* out = (f32x4*)d_out;

    k_all<<<B * CG, 256, 0, stream>>>(x, mask, out);   // 512 blocks
}

// Round 13
// 226.610 us; speedup vs baseline: 2.1272x; 1.6634x over previous
//
#include <hip/hip_runtime.h>
#include <math.h>
#include <stdint.h>

// CausalRevIN: B=16, T=8192, C=128, fp32.
// R13: k1 (cold window) + ONE fused k23 using ticket-ordered decoupled
// lookback (no grid.sync -> registers stay live; R8/R11's spill avoided).
//  k1: x+mask -> aggx/aggn + sub partials + nm nibbles; zeroes flags/ticket.
//  k23: ticket=chunk; prologue prefix(x,nm); sweep A (x->regs, dev2 sums);
//       publish aggd (device-scope) + flag; spin-acquire predecessors' aggd;
//       sweep B finalize from registers; NT store.
constexpr int B = 16;
constexpr int T = 8192;
constexpr int C = 128;
constexpr int CG = C / 4;        // 32 f32x4 channel-groups
constexpr int TBK = 128;         // rows per chunk
constexpr int NCH = T / TBK;     // 64 chunks per batch
constexpr int SUBS = 8;          // 256 threads = SUBS * CG
constexpr int RPT = TBK / SUBS;  // 16 rows per thread
constexpr int NBLK = B * NCH;    // 1024
constexpr float STD_MIN = 1e-5f;
constexpr float MAX_VAL = 100.0f;

using f32x4 = __attribute__((ext_vector_type(4))) float;

__device__ inline f32x4 max1(f32x4 n) {
    f32x4 r;
    #pragma unroll
    for (int j = 0; j < 4; ++j) r[j] = fmaxf(n[j], 1.0f);
    return r;
}
__device__ inline f32x4 rcp4(f32x4 a) {
    f32x4 r;
    #pragma unroll
    for (int j = 0; j < 4; ++j) r[j] = __builtin_amdgcn_rcpf(a[j]);
    return r;
}
__device__ inline f32x4 sqrt4(f32x4 a) {
    f32x4 r;
    #pragma unroll
    for (int j = 0; j < 4; ++j) r[j] = __builtin_amdgcn_sqrtf(a[j]);
    return r;
}
__device__ inline f32x4 decode_nib(unsigned nib) {
    f32x4 r;
    r[0] = (float)(nib & 1u);
    r[1] = (float)((nib >> 1) & 1u);
    r[2] = (float)((nib >> 2) & 1u);
    r[3] = (float)((nib >> 3) & 1u);
    return r;
}

// ---------------- k1: cold sums + sub partials + nm nibbles + flag init ----
__global__ __launch_bounds__(256) void k1_sums(
    const f32x4* __restrict__ x, const f32x4* __restrict__ mask,
    f32x4* __restrict__ aggx, f32x4* __restrict__ aggn,
    f32x4* __restrict__ subx, f32x4* __restrict__ subn,
    uint64_t* __restrict__ nmw, unsigned* __restrict__ flags,
    unsigned* __restrict__ ticket)
{
    __shared__ f32x4 p0[SUBS][CG], p1[SUBS][CG];
    int tid = threadIdx.x, cg = tid & 31, sub = tid >> 5;
    int blk = blockIdx.x, b = blk >> 6, k = blk & (NCH - 1);
    size_t base = ((size_t)b * T + (size_t)k * TBK + (size_t)sub * RPT) * CG + cg;

    if (tid == 0) {
        __hip_atomic_store(&flags[blk], 0u, __ATOMIC_RELAXED,
                           __HIP_MEMORY_SCOPE_AGENT);
        if (blk == 0)
            __hip_atomic_store(ticket, 0u, __ATOMIC_RELAXED,
                               __HIP_MEMORY_SCOPE_AGENT);
    }

    f32x4 sx = {0,0,0,0}, sn = {0,0,0,0};
    uint64_t w = 0;
    #pragma unroll
    for (int r = 0; r < RPT; ++r) {
        f32x4 xv = x[base + (size_t)r * CG];
        f32x4 mv = mask[base + (size_t)r * CG];
        f32x4 nm = 1.0f - mv;
        sx += xv; sn += nm;
        unsigned nib = (unsigned)nm[0] | ((unsigned)nm[1] << 1)
                     | ((unsigned)nm[2] << 2) | ((unsigned)nm[3] << 3);
        w |= (uint64_t)nib << (4 * r);
    }
    nmw[(size_t)blk * 256 + tid] = w;
    size_t so = ((size_t)blk * SUBS + sub) * CG + cg;
    subx[so] = sx;
    subn[so] = sn;
    p0[sub][cg] = sx; p1[sub][cg] = sn;
    __syncthreads();
    if (sub == 0) {
        f32x4 tx = p0[0][cg], tn = p1[0][cg];
        #pragma unroll
        for (int s = 1; s < SUBS; ++s) { tx += p0[s][cg]; tn += p1[s][cg]; }
        aggx[(size_t)blk * CG + cg] = tx;
        aggn[(size_t)blk * CG + cg] = tn;
    }
}

// ---------------- k23: fused dev^2 + finalize (decoupled lookback) ---------
__global__ __launch_bounds__(256) void k23_fused(
    const f32x4* __restrict__ x,
    const f32x4* __restrict__ aggx, const f32x4* __restrict__ aggn,
    const f32x4* __restrict__ subx, const f32x4* __restrict__ subn,
    const uint64_t* __restrict__ nmw,
    float* __restrict__ aggd,            // [NBLK][C] device-scope published
    unsigned* __restrict__ flags, unsigned* __restrict__ ticket,
    f32x4* __restrict__ out)
{
    __shared__ f32x4 p0[SUBS][CG], p1[SUBS][CG];   // 8 KB
    __shared__ int s_ticket;
    int tid = threadIdx.x, cg = tid & 31, sub = tid >> 5;

    if (tid == 0)
        s_ticket = (int)__hip_atomic_fetch_add(ticket, 1u, __ATOMIC_RELAXED,
                                               __HIP_MEMORY_SCOPE_AGENT);
    __syncthreads();
    int blk = s_ticket, b = blk >> 6, k = blk & (NCH - 1);
    size_t base = ((size_t)b * T + (size_t)k * TBK + (size_t)sub * RPT) * CG + cg;

    // --- prologue: chunk prefix (x, nm) + own-sub offsets ------------------
    f32x4 pxp = {0,0,0,0}, pnp = {0,0,0,0};
    for (int j = sub; j < k; j += SUBS) {
        size_t o = ((size_t)(b * NCH + j)) * CG + cg;
        pxp += aggx[o]; pnp += aggn[o];
    }
    p0[sub][cg] = pxp; p1[sub][cg] = pnp;
    __syncthreads();
    f32x4 px = p0[0][cg], pn = p1[0][cg];
    #pragma unroll
    for (int s = 1; s < SUBS; ++s) { px += p0[s][cg]; pn += p1[s][cg]; }

    f32x4 offx = {0,0,0,0}, offn = {0,0,0,0};
    for (int s = 0; s < sub; ++s) {
        size_t so = ((size_t)blk * SUBS + s) * CG + cg;
        offx += subx[so]; offn += subn[so];
    }
    f32x4 rx0 = px + offx, rn0 = pn + offn;
    uint64_t w = nmw[(size_t)blk * 256 + tid];

    // --- sweep A: x -> regs; running mean -> dev^2 sums --------------------
    f32x4 xr[RPT];
    f32x4 rx = rx0, rn = rn0, sd = {0,0,0,0};
    #pragma unroll
    for (int r = 0; r < RPT; ++r) {
        f32x4 xv = x[base + (size_t)r * CG];
        xr[r] = xv;
        f32x4 nm = decode_nib((unsigned)(w >> (4 * r)) & 0xFu);
        rx += xv; rn += nm;
        f32x4 mean = rx * rcp4(max1(rn));
        f32x4 d = (xv - mean) * nm;
        sd += d * d;
    }
    __syncthreads();            // prologue LDS reads complete
    p0[sub][cg] = sd;
    __syncthreads();
    f32x4 offd = {0,0,0,0};
    for (int s = 0; s < sub; ++s) offd += p0[s][cg];
    // publish chunk d2 total (device-scope stores) + release flag
    if (sub == 0) {
        f32x4 td = p0[0][cg];
        #pragma unroll
        for (int s = 1; s < SUBS; ++s) td += p0[s][cg];
        float* dst = &aggd[(size_t)blk * C + cg * 4];
        #pragma unroll
        for (int j = 0; j < 4; ++j)
            __hip_atomic_store(&dst[j], td[j], __ATOMIC_RELAXED,
                               __HIP_MEMORY_SCOPE_AGENT);
    }
    __syncthreads();
    if (tid == 0)
        __hip_atomic_store(&flags[blk], 1u, __ATOMIC_RELEASE,
                           __HIP_MEMORY_SCOPE_AGENT);

    // --- lookback: spin-acquire predecessors' aggd -------------------------
    f32x4 pdp = {0,0,0,0};
    for (int j = sub; j < k; j += SUBS) {
        int pb = b * NCH + j;
        while (__hip_atomic_load(&flags[pb], __ATOMIC_ACQUIRE,
                                 __HIP_MEMORY_SCOPE_AGENT) == 0u)
            __builtin_amdgcn_s_sleep(1);
        const float* src = &aggd[(size_t)pb * C + cg * 4];
        #pragma unroll
        for (int jj = 0; jj < 4; ++jj)
            pdp[jj] += __hip_atomic_load(&src[jj], __ATOMIC_RELAXED,
                                         __HIP_MEMORY_SCOPE_AGENT);
    }
    p1[sub][cg] = pdp;
    __syncthreads();
    f32x4 pd = p1[0][cg];
    #pragma unroll
    for (int s = 1; s < SUBS; ++s) pd += p1[s][cg];
    f32x4 rd = pd + offd;

    // --- sweep B: finalize + clip + NT store (x from registers) ------------
    rx = rx0; rn = rn0;
    #pragma unroll
    for (int r = 0; r < RPT; ++r) {
        f32x4 nm = decode_nib((unsigned)(w >> (4 * r)) & 0xFu);
        rx += xr[r]; rn += nm;
        f32x4 inv = rcp4(max1(rn));
        f32x4 mean = rx * inv;
        f32x4 d = (xr[r] - mean) * nm;
        rd += d * d;
        f32x4 s = sqrt4(rd * inv);
        f32x4 ov;
        #pragma unroll
        for (int j = 0; j < 4; ++j) {
            float invs = (s[j] > STD_MIN) ? __builtin_amdgcn_rcpf(s[j]) : 1.0f;
            float v = (xr[r][j] - mean[j]) * invs;
            ov[j] = fminf(fmaxf(v, -MAX_VAL), MAX_VAL);
        }
        __builtin_nontemporal_store(ov, &out[base + (size_t)r * CG]);
    }
}

// ===========================================================================
extern "C" void kernel_launch(void* const* d_in, const int* in_sizes, int n_in,
                              void* d_out, int out_size, void* d_ws, size_t ws_size,
                              hipStream_t stream) {
    const f32x4* x    = (const f32x4*)d_in[0];
    const f32x4* mask = (const f32x4*)d_in[1];
    f32x4* out = (f32x4*)d_out;

    // ws: aggx/aggn (512 KB each) + aggd (512 KB) + subx/subn (4 MB each)
    //     + nmw (2 MB) + flags (4 KB) + ticket (4 B)
    size_t agg_elems = (size_t)NBLK * CG;            // 32768 f32x4
    size_t sub_elems = (size_t)NBLK * SUBS * CG;     // 262144 f32x4
    f32x4* aggx = (f32x4*)d_ws;
    f32x4* aggn = aggx + agg_elems;
    float* aggd = (float*)(aggn + agg_elems);        // [NBLK][C]
    f32x4* subx = (f32x4*)(aggd + (size_t)NBLK * C);
    f32x4* subn = subx + sub_elems;
    uint64_t* nmw = (uint64_t*)(subn + sub_elems);
    unsigned* flags  = (unsigned*)(nmw + (size_t)NBLK * 256);
    unsigned* ticket = flags + NBLK;

    k1_sums<<<NBLK, 256, 0, stream>>>(x, mask, aggx, aggn, subx, subn,
                                      nmw, flags, ticket);
    k23_fused<<<NBLK, 256, 0, stream>>>(x, aggx, aggn, subx, subn, nmw,
                                        aggd, flags, ticket, out);
}

// Round 14
// 180.552 us; speedup vs baseline: 2.6699x; 1.2551x over previous
//
#include <hip/hip_runtime.h>
#include <math.h>
#include <stdint.h>

// CausalRevIN: B=16, T=8192, C=128, fp32.
// R14: R13's ticket-ordered decoupled lookback with the polling protocol
// fixed: RELAXED parallel polls (1 flag per thread, no cache-invalidating
// acquire storm) + a single __threadfence() per block after observation.
//  k1: x+mask -> aggx/aggn + sub partials + nm nibbles; zeroes flags/ticket.
//  k23: ticket=chunk; prefix(x,nm) prologue; sweep A (x->regs, dev2);
//       publish aggd+flag; relaxed-poll predecessors; fence; sweep B; NT out.
constexpr int B = 16;
constexpr int T = 8192;
constexpr int C = 128;
constexpr int CG = C / 4;        // 32 f32x4 channel-groups
constexpr int TBK = 128;         // rows per chunk
constexpr int NCH = T / TBK;     // 64 chunks per batch
constexpr int SUBS = 8;          // 256 threads = SUBS * CG
constexpr int RPT = TBK / SUBS;  // 16 rows per thread
constexpr int NBLK = B * NCH;    // 1024
constexpr float STD_MIN = 1e-5f;
constexpr float MAX_VAL = 100.0f;

using f32x4 = __attribute__((ext_vector_type(4))) float;

__device__ inline f32x4 max1(f32x4 n) {
    f32x4 r;
    #pragma unroll
    for (int j = 0; j < 4; ++j) r[j] = fmaxf(n[j], 1.0f);
    return r;
}
__device__ inline f32x4 rcp4(f32x4 a) {
    f32x4 r;
    #pragma unroll
    for (int j = 0; j < 4; ++j) r[j] = __builtin_amdgcn_rcpf(a[j]);
    return r;
}
__device__ inline f32x4 sqrt4(f32x4 a) {
    f32x4 r;
    #pragma unroll
    for (int j = 0; j < 4; ++j) r[j] = __builtin_amdgcn_sqrtf(a[j]);
    return r;
}
__device__ inline f32x4 decode_nib(unsigned nib) {
    f32x4 r;
    r[0] = (float)(nib & 1u);
    r[1] = (float)((nib >> 1) & 1u);
    r[2] = (float)((nib >> 2) & 1u);
    r[3] = (float)((nib >> 3) & 1u);
    return r;
}

// ---------------- k1: cold sums + sub partials + nm nibbles + flag init ----
__global__ __launch_bounds__(256) void k1_sums(
    const f32x4* __restrict__ x, const f32x4* __restrict__ mask,
    f32x4* __restrict__ aggx, f32x4* __restrict__ aggn,
    f32x4* __restrict__ subx, f32x4* __restrict__ subn,
    uint64_t* __restrict__ nmw, unsigned* __restrict__ flags,
    unsigned* __restrict__ ticket)
{
    __shared__ f32x4 p0[SUBS][CG], p1[SUBS][CG];
    int tid = threadIdx.x, cg = tid & 31, sub = tid >> 5;
    int blk = blockIdx.x, b = blk >> 6, k = blk & (NCH - 1);
    size_t base = ((size_t)b * T + (size_t)k * TBK + (size_t)sub * RPT) * CG + cg;

    if (tid == 0) {
        __hip_atomic_store(&flags[blk], 0u, __ATOMIC_RELAXED,
                           __HIP_MEMORY_SCOPE_AGENT);
        if (blk == 0)
            __hip_atomic_store(ticket, 0u, __ATOMIC_RELAXED,
                               __HIP_MEMORY_SCOPE_AGENT);
    }

    f32x4 sx = {0,0,0,0}, sn = {0,0,0,0};
    uint64_t w = 0;
    #pragma unroll
    for (int r = 0; r < RPT; ++r) {
        f32x4 xv = x[base + (size_t)r * CG];
        f32x4 mv = mask[base + (size_t)r * CG];
        f32x4 nm = 1.0f - mv;
        sx += xv; sn += nm;
        unsigned nib = (unsigned)nm[0] | ((unsigned)nm[1] << 1)
                     | ((unsigned)nm[2] << 2) | ((unsigned)nm[3] << 3);
        w |= (uint64_t)nib << (4 * r);
    }
    nmw[(size_t)blk * 256 + tid] = w;
    size_t so = ((size_t)blk * SUBS + sub) * CG + cg;
    subx[so] = sx;
    subn[so] = sn;
    p0[sub][cg] = sx; p1[sub][cg] = sn;
    __syncthreads();
    if (sub == 0) {
        f32x4 tx = p0[0][cg], tn = p1[0][cg];
        #pragma unroll
        for (int s = 1; s < SUBS; ++s) { tx += p0[s][cg]; tn += p1[s][cg]; }
        aggx[(size_t)blk * CG + cg] = tx;
        aggn[(size_t)blk * CG + cg] = tn;
    }
}

// ---------------- k23: fused dev^2 + finalize (relaxed lookback) -----------
__global__ __launch_bounds__(256) void k23_fused(
    const f32x4* __restrict__ x,
    const f32x4* __restrict__ aggx, const f32x4* __restrict__ aggn,
    const f32x4* __restrict__ subx, const f32x4* __restrict__ subn,
    const uint64_t* __restrict__ nmw,
    float* __restrict__ aggd,            // [NBLK][C] coherence-point data
    unsigned* __restrict__ flags, unsigned* __restrict__ ticket,
    f32x4* __restrict__ out)
{
    __shared__ f32x4 p0[SUBS][CG], p1[SUBS][CG];   // 8 KB
    __shared__ int s_ticket;
    int tid = threadIdx.x, cg = tid & 31, sub = tid >> 5;

    if (tid == 0)
        s_ticket = (int)__hip_atomic_fetch_add(ticket, 1u, __ATOMIC_RELAXED,
                                               __HIP_MEMORY_SCOPE_AGENT);
    __syncthreads();
    int blk = s_ticket, b = blk >> 6, k = blk & (NCH - 1);
    size_t base = ((size_t)b * T + (size_t)k * TBK + (size_t)sub * RPT) * CG + cg;

    // --- prologue: chunk prefix (x, nm) + own-sub offsets ------------------
    f32x4 pxp = {0,0,0,0}, pnp = {0,0,0,0};
    for (int j = sub; j < k; j += SUBS) {
        size_t o = ((size_t)(b * NCH + j)) * CG + cg;
        pxp += aggx[o]; pnp += aggn[o];
    }
    p0[sub][cg] = pxp; p1[sub][cg] = pnp;
    __syncthreads();
    f32x4 px = p0[0][cg], pn = p1[0][cg];
    #pragma unroll
    for (int s = 1; s < SUBS; ++s) { px += p0[s][cg]; pn += p1[s][cg]; }

    f32x4 offx = {0,0,0,0}, offn = {0,0,0,0};
    for (int s = 0; s < sub; ++s) {
        size_t so = ((size_t)blk * SUBS + s) * CG + cg;
        offx += subx[so]; offn += subn[so];
    }
    f32x4 rx0 = px + offx, rn0 = pn + offn;
    uint64_t w = nmw[(size_t)blk * 256 + tid];

    // --- sweep A: x -> regs; running mean -> dev^2 sums --------------------
    f32x4 xr[RPT];
    f32x4 rx = rx0, rn = rn0, sd = {0,0,0,0};
    #pragma unroll
    for (int r = 0; r < RPT; ++r) {
        f32x4 xv = x[base + (size_t)r * CG];
        xr[r] = xv;
        f32x4 nm = decode_nib((unsigned)(w >> (4 * r)) & 0xFu);
        rx += xv; rn += nm;
        f32x4 mean = rx * rcp4(max1(rn));
        f32x4 d = (xv - mean) * nm;
        sd += d * d;
    }
    __syncthreads();            // prologue LDS reads complete
    p0[sub][cg] = sd;
    __syncthreads();
    f32x4 offd = {0,0,0,0};
    for (int s = 0; s < sub; ++s) offd += p0[s][cg];
    // publish chunk d2 total (coherence-point stores) + release flag
    if (sub == 0) {
        f32x4 td = p0[0][cg];
        #pragma unroll
        for (int s = 1; s < SUBS; ++s) td += p0[s][cg];
        float* dst = &aggd[(size_t)blk * C + cg * 4];
        #pragma unroll
        for (int j = 0; j < 4; ++j)
            __hip_atomic_store(&dst[j], td[j], __ATOMIC_RELAXED,
                               __HIP_MEMORY_SCOPE_AGENT);
    }
    __syncthreads();
    if (tid == 0)
        __hip_atomic_store(&flags[blk], 1u, __ATOMIC_RELEASE,
                           __HIP_MEMORY_SCOPE_AGENT);

    // --- lookback: RELAXED parallel poll (1 flag/thread), single fence -----
    if (tid < k) {
        while (__hip_atomic_load(&flags[b * NCH + tid], __ATOMIC_RELAXED,
                                 __HIP_MEMORY_SCOPE_AGENT) == 0u)
            __builtin_amdgcn_s_sleep(2);
    }
    __syncthreads();
    __threadfence();            // one acquire-strength fence per thread

    f32x4 pdp = {0,0,0,0};
    for (int j = sub; j < k; j += SUBS) {
        const float* src = &aggd[(size_t)(b * NCH + j) * C + cg * 4];
        #pragma unroll
        for (int jj = 0; jj < 4; ++jj)
            pdp[jj] += __hip_atomic_load(&src[jj], __ATOMIC_RELAXED,
                                         __HIP_MEMORY_SCOPE_AGENT);
    }
    p1[sub][cg] = pdp;
    __syncthreads();
    f32x4 pd = p1[0][cg];
    #pragma unroll
    for (int s = 1; s < SUBS; ++s) pd += p1[s][cg];
    f32x4 rd = pd + offd;

    // --- sweep B: finalize + clip + NT store (x from registers) ------------
    rx = rx0; rn = rn0;
    #pragma unroll
    for (int r = 0; r < RPT; ++r) {
        f32x4 nm = decode_nib((unsigned)(w >> (4 * r)) & 0xFu);
        rx += xr[r]; rn += nm;
        f32x4 inv = rcp4(max1(rn));
        f32x4 mean = rx * inv;
        f32x4 d = (xr[r] - mean) * nm;
        rd += d * d;
        f32x4 s = sqrt4(rd * inv);
        f32x4 ov;
        #pragma unroll
        for (int j = 0; j < 4; ++j) {
            float invs = (s[j] > STD_MIN) ? __builtin_amdgcn_rcpf(s[j]) : 1.0f;
            float v = (xr[r][j] - mean[j]) * invs;
            ov[j] = fminf(fmaxf(v, -MAX_VAL), MAX_VAL);
        }
        __builtin_nontemporal_store(ov, &out[base + (size_t)r * CG]);
    }
}

// ===========================================================================
extern "C" void kernel_launch(void* const* d_in, const int* in_sizes, int n_in,
                              void* d_out, int out_size, void* d_ws, size_t ws_size,
                              hipStream_t stream) {
    const f32x4* x    = (const f32x4*)d_in[0];
    const f32x4* mask = (const f32x4*)d_in[1];
    f32x4* out = (f32x4*)d_out;

    // ws: aggx/aggn (512 KB each) + aggd (512 KB) + subx/subn (4 MB each)
    //     + nmw (2 MB) + flags (4 KB) + ticket (4 B)
    size_t agg_elems = (size_t)NBLK * CG;            // 32768 f32x4
    size_t sub_elems = (size_t)NBLK * SUBS * CG;     // 262144 f32x4
    f32x4* aggx = (f32x4*)d_ws;
    f32x4* aggn = aggx + agg_elems;
    float* aggd = (float*)(aggn + agg_elems);        // [NBLK][C]
    f32x4* subx = (f32x4*)(aggd + (size_t)NBLK * C);
    f32x4* subn = subx + sub_elems;
    uint64_t* nmw = (uint64_t*)(subn + sub_elems);
    unsigned* flags  = (unsigned*)(nmw + (size_t)NBLK * 256);
    unsigned* ticket = flags + NBLK;

    k1_sums<<<NBLK, 256, 0, stream>>>(x, mask, aggx, aggn, subx, subn,
                                      nmw, flags, ticket);
    k23_fused<<<NBLK, 256, 0, stream>>>(x, aggx, aggn, subx, subn, nmw,
                                        aggd, flags, ticket, out);
}

// Round 15
// 72.580 us; speedup vs baseline: 6.6417x; 2.4876x over previous
//
#include <hip/hip_runtime.h>
#include <math.h>
#include <stdint.h>

// CausalRevIN: B=16, T=8192, C=128, fp32.
// R15 = R10 (best: 71.5us) with ONE change: k3 writes out with normal cached
// stores (not NT). Theory: harness re-poisons out (L3-dirty) every replay;
// cached stores get absorbed by those warm lines instead of adding 67 MB of
// NT HBM writes on top of the poison writeback.
constexpr int B = 16;
constexpr int T = 8192;
constexpr int C = 128;
constexpr int CG = C / 4;        // 32 f32x4 channel-groups
constexpr int TBK = 128;         // rows per chunk/block
constexpr int NCH = T / TBK;     // 64 chunks per batch
constexpr int SUBS = 8;          // 256 threads = SUBS * CG
constexpr int RPT = TBK / SUBS;  // 16 rows per thread
constexpr float STD_MIN = 1e-5f;
constexpr float MAX_VAL = 100.0f;

using f32x4 = __attribute__((ext_vector_type(4))) float;

__device__ inline f32x4 max1(f32x4 n) {
    f32x4 r;
    #pragma unroll
    for (int j = 0; j < 4; ++j) r[j] = fmaxf(n[j], 1.0f);
    return r;
}
__device__ inline f32x4 rcp4(f32x4 a) {
    f32x4 r;
    #pragma unroll
    for (int j = 0; j < 4; ++j) r[j] = __builtin_amdgcn_rcpf(a[j]);
    return r;
}
__device__ inline f32x4 sqrt4(f32x4 a) {
    f32x4 r;
    #pragma unroll
    for (int j = 0; j < 4; ++j) r[j] = __builtin_amdgcn_sqrtf(a[j]);
    return r;
}
__device__ inline f32x4 decode_nib(unsigned nib) {
    f32x4 r;
    r[0] = (float)(nib & 1u);
    r[1] = (float)((nib >> 1) & 1u);
    r[2] = (float)((nib >> 2) & 1u);
    r[3] = (float)((nib >> 3) & 1u);
    return r;
}

// ---------------- k1: cold sums + sub partials + nm nibbles ----------------
__global__ __launch_bounds__(256) void k1_sums(
    const f32x4* __restrict__ x, const f32x4* __restrict__ mask,
    f32x4* __restrict__ aggx, f32x4* __restrict__ aggn,
    f32x4* __restrict__ subx, f32x4* __restrict__ subn,
    uint64_t* __restrict__ nmw)
{
    __shared__ f32x4 p0[SUBS][CG], p1[SUBS][CG];
    int tid = threadIdx.x, cg = tid & 31, sub = tid >> 5;
    int blk = blockIdx.x, b = blk >> 6, k = blk & (NCH - 1);
    size_t base = ((size_t)b * T + (size_t)k * TBK + (size_t)sub * RPT) * CG + cg;

    f32x4 sx = {0,0,0,0}, sn = {0,0,0,0};
    uint64_t w = 0;
    #pragma unroll
    for (int r = 0; r < RPT; ++r) {
        f32x4 xv = x[base + (size_t)r * CG];
        f32x4 mv = mask[base + (size_t)r * CG];
        f32x4 nm = 1.0f - mv;
        sx += xv; sn += nm;
        unsigned nib = (unsigned)nm[0] | ((unsigned)nm[1] << 1)
                     | ((unsigned)nm[2] << 2) | ((unsigned)nm[3] << 3);
        w |= (uint64_t)nib << (4 * r);
    }
    nmw[(size_t)blk * 256 + tid] = w;
    size_t so = ((size_t)blk * SUBS + sub) * CG + cg;
    subx[so] = sx;
    subn[so] = sn;
    p0[sub][cg] = sx; p1[sub][cg] = sn;
    __syncthreads();
    if (sub == 0) {
        f32x4 tx = p0[0][cg], tn = p1[0][cg];
        #pragma unroll
        for (int s = 1; s < SUBS; ++s) { tx += p0[s][cg]; tn += p1[s][cg]; }
        aggx[(size_t)blk * CG + cg] = tx;
        aggn[(size_t)blk * CG + cg] = tn;
    }
}

// ---------------- k2: single dev^2 sweep -----------------------------------
__global__ __launch_bounds__(256) void k2_dev2(
    const f32x4* __restrict__ x,
    const f32x4* __restrict__ aggx, const f32x4* __restrict__ aggn,
    const f32x4* __restrict__ subx, const f32x4* __restrict__ subn,
    const uint64_t* __restrict__ nmw,
    f32x4* __restrict__ aggd, f32x4* __restrict__ subd)
{
    __shared__ f32x4 p0[SUBS][CG], p1[SUBS][CG];
    int tid = threadIdx.x, cg = tid & 31, sub = tid >> 5;
    int blk = blockIdx.x, b = blk >> 6, k = blk & (NCH - 1);
    size_t base = ((size_t)b * T + (size_t)k * TBK + (size_t)sub * RPT) * CG + cg;

    // chunk-level predecessor prefix (parallel over subs)
    f32x4 pxp = {0,0,0,0}, pnp = {0,0,0,0};
    for (int j = sub; j < k; j += SUBS) {
        size_t o = ((size_t)(b * NCH + j)) * CG + cg;
        pxp += aggx[o]; pnp += aggn[o];
    }
    p0[sub][cg] = pxp; p1[sub][cg] = pnp;
    __syncthreads();
    f32x4 px = p0[0][cg], pn = p1[0][cg];
    #pragma unroll
    for (int s = 1; s < SUBS; ++s) { px += p0[s][cg]; pn += p1[s][cg]; }

    // own-chunk exclusive sub offsets (from k1's partials)
    f32x4 offx = {0,0,0,0}, offn = {0,0,0,0};
    for (int s = 0; s < sub; ++s) {
        size_t so = ((size_t)blk * SUBS + s) * CG + cg;
        offx += subx[so]; offn += subn[so];
    }
    f32x4 rx = px + offx, rn = pn + offn;
    uint64_t w = nmw[(size_t)blk * 256 + tid];

    // single sweep: running mean -> dev^2 sums
    f32x4 sd = {0,0,0,0};
    #pragma unroll
    for (int r = 0; r < RPT; ++r) {
        f32x4 xv = x[base + (size_t)r * CG];
        f32x4 nm = decode_nib((unsigned)(w >> (4 * r)) & 0xFu);
        rx += xv; rn += nm;
        f32x4 mean = rx * rcp4(max1(rn));
        f32x4 d = (xv - mean) * nm;
        sd += d * d;
    }
    subd[((size_t)blk * SUBS + sub) * CG + cg] = sd;
    __syncthreads();            // before p0 reuse
    p0[sub][cg] = sd;
    __syncthreads();
    if (sub == 0) {
        f32x4 td = p0[0][cg];
        #pragma unroll
        for (int s = 1; s < SUBS; ++s) td += p0[s][cg];
        aggd[(size_t)blk * CG + cg] = td;
    }
}

// ---------------- k3: single finalize sweep, CACHED stores -----------------
__global__ __launch_bounds__(256) void k3_final(
    const f32x4* __restrict__ x,
    const f32x4* __restrict__ aggx, const f32x4* __restrict__ aggn,
    const f32x4* __restrict__ aggd,
    const f32x4* __restrict__ subx, const f32x4* __restrict__ subn,
    const f32x4* __restrict__ subd,
    const uint64_t* __restrict__ nmw, f32x4* __restrict__ out)
{
    __shared__ f32x4 p0[SUBS][CG], p1[SUBS][CG], p2[SUBS][CG];
    int tid = threadIdx.x, cg = tid & 31, sub = tid >> 5;
    int blk = blockIdx.x, b = blk >> 6, k = blk & (NCH - 1);
    size_t base = ((size_t)b * T + (size_t)k * TBK + (size_t)sub * RPT) * CG + cg;

    // chunk-level predecessor prefixes (x, nm, d2)
    f32x4 pxp = {0,0,0,0}, pnp = {0,0,0,0}, pdp = {0,0,0,0};
    for (int j = sub; j < k; j += SUBS) {
        size_t o = ((size_t)(b * NCH + j)) * CG + cg;
        pxp += aggx[o]; pnp += aggn[o]; pdp += aggd[o];
    }
    p0[sub][cg] = pxp; p1[sub][cg] = pnp; p2[sub][cg] = pdp;
    __syncthreads();
    f32x4 px = p0[0][cg], pn = p1[0][cg], pd = p2[0][cg];
    #pragma unroll
    for (int s = 1; s < SUBS; ++s) {
        px += p0[s][cg]; pn += p1[s][cg]; pd += p2[s][cg];
    }

    // own-chunk exclusive sub offsets
    f32x4 offx = {0,0,0,0}, offn = {0,0,0,0}, offd = {0,0,0,0};
    for (int s = 0; s < sub; ++s) {
        size_t so = ((size_t)blk * SUBS + s) * CG + cg;
        offx += subx[so]; offn += subn[so]; offd += subd[so];
    }
    f32x4 rx = px + offx, rn = pn + offn, rd = pd + offd;
    uint64_t w = nmw[(size_t)blk * 256 + tid];

    // single sweep: finalize + clip + cached store
    #pragma unroll
    for (int r = 0; r < RPT; ++r) {
        f32x4 xv = x[base + (size_t)r * CG];
        f32x4 nm = decode_nib((unsigned)(w >> (4 * r)) & 0xFu);
        rx += xv; rn += nm;
        f32x4 inv = rcp4(max1(rn));
        f32x4 mean = rx * inv;
        f32x4 d = (xv - mean) * nm;
        rd += d * d;
        f32x4 s = sqrt4(rd * inv);
        f32x4 ov;
        #pragma unroll
        for (int j = 0; j < 4; ++j) {
            float invs = (s[j] > STD_MIN) ? __builtin_amdgcn_rcpf(s[j]) : 1.0f;
            float v = (xv[j] - mean[j]) * invs;
            ov[j] = fminf(fmaxf(v, -MAX_VAL), MAX_VAL);
        }
        out[base + (size_t)r * CG] = ov;   // cached: absorbed by poison-warm L3 lines
    }
}

// ===========================================================================
extern "C" void kernel_launch(void* const* d_in, const int* in_sizes, int n_in,
                              void* d_out, int out_size, void* d_ws, size_t ws_size,
                              hipStream_t stream) {
    const f32x4* x    = (const f32x4*)d_in[0];
    const f32x4* mask = (const f32x4*)d_in[1];
    f32x4* out = (f32x4*)d_out;

    // ws: aggx/aggn/aggd (512 KB each) + subx/subn/subd (4 MB each) + nmw (2 MB)
    size_t agg_elems = (size_t)B * NCH * CG;          // 32768 f32x4
    size_t sub_elems = (size_t)B * NCH * SUBS * CG;   // 262144 f32x4
    f32x4* aggx = (f32x4*)d_ws;
    f32x4* aggn = aggx + agg_elems;
    f32x4* aggd = aggn + agg_elems;
    f32x4* subx = aggd + agg_elems;
    f32x4* subn = subx + sub_elems;
    f32x4* subd = subn + sub_elems;
    uint64_t* nmw = (uint64_t*)(subd + sub_elems);

    int grid = B * NCH;   // 1024

    k1_sums<<<grid, 256, 0, stream>>>(x, mask, aggx, aggn, subx, subn, nmw);
    k2_dev2<<<grid, 256, 0, stream>>>(x, aggx, aggn, subx, subn, nmw, aggd, subd);
    k3_final<<<grid, 256, 0, stream>>>(x, aggx, aggn, aggd, subx, subn, subd, nmw, out);
}

// Round 17
// 69.560 us; speedup vs baseline: 6.9300x; 1.0434x over previous
//
#include <hip/hip_runtime.h>
#include <math.h>
#include <stdint.h>

// CausalRevIN: B=16, T=8192, C=128, fp32.
// FINAL (= R10, session best 71.5us): 3 dispatches, each single-sweep over x.
//  k1 (cold window, rate-capped by harness replay environment): x+mask ->
//     chunk aggregates aggx/aggn + per-sub partials + nm nibbles (uint64/thr).
//  k2: chunk-prefix prologue (L2-resident aggregates) + own-sub offsets +
//     one dev^2 sweep -> aggd + subd.
//  k3: 3-array prologue + offsets + one finalize sweep, NT stores.
// Session findings: k1's ~44-48us is environmental (65MB cold fetch @1.5TB/s,
// invariant across 10 structural variants, concurrent with ~268MB harness
// poison traffic); k2+k3 ~26us run warm at ~7.4TB/s effective. grid.sync
// fusion spills x-registers (R8/R11); lookback sync costs 150-200us (R13/14);
// bf16 x-compression fails numerics via 1/std amplification (R16).
constexpr int B = 16;
constexpr int T = 8192;
constexpr int C = 128;
constexpr int CG = C / 4;        // 32 f32x4 channel-groups
constexpr int TBK = 128;         // rows per chunk/block
constexpr int NCH = T / TBK;     // 64 chunks per batch
constexpr int SUBS = 8;          // 256 threads = SUBS * CG
constexpr int RPT = TBK / SUBS;  // 16 rows per thread
constexpr float STD_MIN = 1e-5f;
constexpr float MAX_VAL = 100.0f;

using f32x4 = __attribute__((ext_vector_type(4))) float;

__device__ inline f32x4 max1(f32x4 n) {
    f32x4 r;
    #pragma unroll
    for (int j = 0; j < 4; ++j) r[j] = fmaxf(n[j], 1.0f);
    return r;
}
__device__ inline f32x4 rcp4(f32x4 a) {
    f32x4 r;
    #pragma unroll
    for (int j = 0; j < 4; ++j) r[j] = __builtin_amdgcn_rcpf(a[j]);
    return r;
}
__device__ inline f32x4 sqrt4(f32x4 a) {
    f32x4 r;
    #pragma unroll
    for (int j = 0; j < 4; ++j) r[j] = __builtin_amdgcn_sqrtf(a[j]);
    return r;
}
__device__ inline f32x4 decode_nib(unsigned nib) {
    f32x4 r;
    r[0] = (float)(nib & 1u);
    r[1] = (float)((nib >> 1) & 1u);
    r[2] = (float)((nib >> 2) & 1u);
    r[3] = (float)((nib >> 3) & 1u);
    return r;
}

// ---------------- k1: cold sums + sub partials + nm nibbles ----------------
__global__ __launch_bounds__(256) void k1_sums(
    const f32x4* __restrict__ x, const f32x4* __restrict__ mask,
    f32x4* __restrict__ aggx, f32x4* __restrict__ aggn,
    f32x4* __restrict__ subx, f32x4* __restrict__ subn,
    uint64_t* __restrict__ nmw)
{
    __shared__ f32x4 p0[SUBS][CG], p1[SUBS][CG];
    int tid = threadIdx.x, cg = tid & 31, sub = tid >> 5;
    int blk = blockIdx.x, b = blk >> 6, k = blk & (NCH - 1);
    size_t base = ((size_t)b * T + (size_t)k * TBK + (size_t)sub * RPT) * CG + cg;

    f32x4 sx = {0,0,0,0}, sn = {0,0,0,0};
    uint64_t w = 0;
    #pragma unroll
    for (int r = 0; r < RPT; ++r) {
        f32x4 xv = x[base + (size_t)r * CG];
        f32x4 mv = mask[base + (size_t)r * CG];
        f32x4 nm = 1.0f - mv;
        sx += xv; sn += nm;
        unsigned nib = (unsigned)nm[0] | ((unsigned)nm[1] << 1)
                     | ((unsigned)nm[2] << 2) | ((unsigned)nm[3] << 3);
        w |= (uint64_t)nib << (4 * r);
    }
    nmw[(size_t)blk * 256 + tid] = w;
    size_t so = ((size_t)blk * SUBS + sub) * CG + cg;
    subx[so] = sx;
    subn[so] = sn;
    p0[sub][cg] = sx; p1[sub][cg] = sn;
    __syncthreads();
    if (sub == 0) {
        f32x4 tx = p0[0][cg], tn = p1[0][cg];
        #pragma unroll
        for (int s = 1; s < SUBS; ++s) { tx += p0[s][cg]; tn += p1[s][cg]; }
        aggx[(size_t)blk * CG + cg] = tx;
        aggn[(size_t)blk * CG + cg] = tn;
    }
}

// ---------------- k2: single dev^2 sweep -----------------------------------
__global__ __launch_bounds__(256) void k2_dev2(
    const f32x4* __restrict__ x,
    const f32x4* __restrict__ aggx, const f32x4* __restrict__ aggn,
    const f32x4* __restrict__ subx, const f32x4* __restrict__ subn,
    const uint64_t* __restrict__ nmw,
    f32x4* __restrict__ aggd, f32x4* __restrict__ subd)
{
    __shared__ f32x4 p0[SUBS][CG], p1[SUBS][CG];
    int tid = threadIdx.x, cg = tid & 31, sub = tid >> 5;
    int blk = blockIdx.x, b = blk >> 6, k = blk & (NCH - 1);
    size_t base = ((size_t)b * T + (size_t)k * TBK + (size_t)sub * RPT) * CG + cg;

    // chunk-level predecessor prefix (parallel over subs)
    f32x4 pxp = {0,0,0,0}, pnp = {0,0,0,0};
    for (int j = sub; j < k; j += SUBS) {
        size_t o = ((size_t)(b * NCH + j)) * CG + cg;
        pxp += aggx[o]; pnp += aggn[o];
    }
    p0[sub][cg] = pxp; p1[sub][cg] = pnp;
    __syncthreads();
    f32x4 px = p0[0][cg], pn = p1[0][cg];
    #pragma unroll
    for (int s = 1; s < SUBS; ++s) { px += p0[s][cg]; pn += p1[s][cg]; }

    // own-chunk exclusive sub offsets (from k1's partials)
    f32x4 offx = {0,0,0,0}, offn = {0,0,0,0};
    for (int s = 0; s < sub; ++s) {
        size_t so = ((size_t)blk * SUBS + s) * CG + cg;
        offx += subx[so]; offn += subn[so];
    }
    f32x4 rx = px + offx, rn = pn + offn;
    uint64_t w = nmw[(size_t)blk * 256 + tid];

    // single sweep: running mean -> dev^2 sums
    f32x4 sd = {0,0,0,0};
    #pragma unroll
    for (int r = 0; r < RPT; ++r) {
        f32x4 xv = x[base + (size_t)r * CG];
        f32x4 nm = decode_nib((unsigned)(w >> (4 * r)) & 0xFu);
        rx += xv; rn += nm;
        f32x4 mean = rx * rcp4(max1(rn));
        f32x4 d = (xv - mean) * nm;
        sd += d * d;
    }
    subd[((size_t)blk * SUBS + sub) * CG + cg] = sd;
    __syncthreads();            // before p0 reuse
    p0[sub][cg] = sd;
    __syncthreads();
    if (sub == 0) {
        f32x4 td = p0[0][cg];
        #pragma unroll
        for (int s = 1; s < SUBS; ++s) td += p0[s][cg];
        aggd[(size_t)blk * CG + cg] = td;
    }
}

// ---------------- k3: single finalize sweep, NT stores ---------------------
__global__ __launch_bounds__(256) void k3_final(
    const f32x4* __restrict__ x,
    const f32x4* __restrict__ aggx, const f32x4* __restrict__ aggn,
    const f32x4* __restrict__ aggd,
    const f32x4* __restrict__ subx, const f32x4* __restrict__ subn,
    const f32x4* __restrict__ subd,
    const uint64_t* __restrict__ nmw, f32x4* __restrict__ out)
{
    __shared__ f32x4 p0[SUBS][CG], p1[SUBS][CG], p2[SUBS][CG];
    int tid = threadIdx.x, cg = tid & 31, sub = tid >> 5;
    int blk = blockIdx.x, b = blk >> 6, k = blk & (NCH - 1);
    size_t base = ((size_t)b * T + (size_t)k * TBK + (size_t)sub * RPT) * CG + cg;

    // chunk-level predecessor prefixes (x, nm, d2)
    f32x4 pxp = {0,0,0,0}, pnp = {0,0,0,0}, pdp = {0,0,0,0};
    for (int j = sub; j < k; j += SUBS) {
        size_t o = ((size_t)(b * NCH + j)) * CG + cg;
        pxp += aggx[o]; pnp += aggn[o]; pdp += aggd[o];
    }
    p0[sub][cg] = pxp; p1[sub][cg] = pnp; p2[sub][cg] = pdp;
    __syncthreads();
    f32x4 px = p0[0][cg], pn = p1[0][cg], pd = p2[0][cg];
    #pragma unroll
    for (int s = 1; s < SUBS; ++s) {
        px += p0[s][cg]; pn += p1[s][cg]; pd += p2[s][cg];
    }

    // own-chunk exclusive sub offsets
    f32x4 offx = {0,0,0,0}, offn = {0,0,0,0}, offd = {0,0,0,0};
    for (int s = 0; s < sub; ++s) {
        size_t so = ((size_t)blk * SUBS + s) * CG + cg;
        offx += subx[so]; offn += subn[so]; offd += subd[so];
    }
    f32x4 rx = px + offx, rn = pn + offn, rd = pd + offd;
    uint64_t w = nmw[(size_t)blk * 256 + tid];

    // single sweep: finalize + clip + NT store
    #pragma unroll
    for (int r = 0; r < RPT; ++r) {
        f32x4 xv = x[base + (size_t)r * CG];
        f32x4 nm = decode_nib((unsigned)(w >> (4 * r)) & 0xFu);
        rx += xv; rn += nm;
        f32x4 inv = rcp4(max1(rn));
        f32x4 mean = rx * inv;
        f32x4 d = (xv - mean) * nm;
        rd += d * d;
        f32x4 s = sqrt4(rd * inv);
        f32x4 ov;
        #pragma unroll
        for (int j = 0; j < 4; ++j) {
            float invs = (s[j] > STD_MIN) ? __builtin_amdgcn_rcpf(s[j]) : 1.0f;
            float v = (xv[j] - mean[j]) * invs;
            ov[j] = fminf(fmaxf(v, -MAX_VAL), MAX_VAL);
        }
        __builtin_nontemporal_store(ov, &out[base + (size_t)r * CG]);
    }
}

// ===========================================================================
extern "C" void kernel_launch(void* const* d_in, const int* in_sizes, int n_in,
                              void* d_out, int out_size, void* d_ws, size_t ws_size,
                              hipStream_t stream) {
    const f32x4* x    = (const f32x4*)d_in[0];
    const f32x4* mask = (const f32x4*)d_in[1];
    f32x4* out = (f32x4*)d_out;

    // ws: aggx/aggn/aggd (512 KB each) + subx/subn/subd (4 MB each) + nmw (2 MB)
    size_t agg_elems = (size_t)B * NCH * CG;          // 32768 f32x4
    size_t sub_elems = (size_t)B * NCH * SUBS * CG;   // 262144 f32x4
    f32x4* aggx = (f32x4*)d_ws;
    f32x4* aggn = aggx + agg_elems;
    f32x4* aggd = aggn + agg_elems;
    f32x4* subx = aggd + agg_elems;
    f32x4* subn = subx + sub_elems;
    f32x4* subd = subn + sub_elems;
    uint64_t* nmw = (uint64_t*)(subd + sub_elems);

    int grid = B * NCH;   // 1024

    k1_sums<<<grid, 256, 0, stream>>>(x, mask, aggx, aggn, subx, subn, nmw);
    k2_dev2<<<grid, 256, 0, stream>>>(x, aggx, aggn, subx, subn, nmw, aggd, subd);
    k3_final<<<grid, 256, 0, stream>>>(x, aggx, aggn, aggd, subx, subn, subd, nmw, out);
}